// Round 3
// baseline (678.763 us; speedup 1.0000x reference)
//
#include <hip/hip_runtime.h>

#define IN_CH 128
#define HEADS 4
#define OUT_CH 32
#define HC 128           // HEADS*OUT_CH
#define SCORE_BLOCKS 4096
#define CHUNK 2048       // scan chunk (256 thr x 8)

__device__ __forceinline__ unsigned flip_f32(float x) {
  unsigned u = __float_as_uint(x);
  return (u & 0x80000000u) ? ~u : (u | 0x80000000u);
}
__device__ __forceinline__ float unflip_f32(unsigned k) {
  unsigned u = (k & 0x80000000u) ? (k ^ 0x80000000u) : ~k;
  return __uint_as_float(u);
}
__device__ __forceinline__ float fast_tanh(float x) {
  return 1.f - 2.f / (__expf(2.f * x) + 1.f);
}

// proj[N][128] = x[N][128] @ W[128][128]
__global__ __launch_bounds__(256) void gemm_xW(const float* __restrict__ x,
                                               const float* __restrict__ W,
                                               float* __restrict__ proj, int N) {
  __shared__ float xs[128][132];
  __shared__ float ws[128][128];
  const int tid = threadIdx.x;
  const int row0 = blockIdx.x * 128;

  {
    const float4* Wv = (const float4*)W;
    float4* wsv = (float4*)ws;
#pragma unroll
    for (int i = 0; i < 16; ++i) wsv[i * 256 + tid] = Wv[i * 256 + tid];
  }
  {
    const int r = tid >> 1;
    const int k0 = (tid & 1) * 64;
    const int grow = row0 + r;
    const bool valid = grow < N;
    const float4* src = (const float4*)(x + (size_t)grow * IN_CH + k0);
#pragma unroll
    for (int i = 0; i < 16; ++i) {
      float4 v = valid ? src[i] : make_float4(0.f, 0.f, 0.f, 0.f);
      const int k = k0 + i * 4;
      xs[k][r] = v.x; xs[k + 1][r] = v.y; xs[k + 2][r] = v.z; xs[k + 3][r] = v.w;
    }
  }
  __syncthreads();

  const int cg = tid & 15;
  const int rg = tid >> 4;
  float acc[8][8];
#pragma unroll
  for (int r = 0; r < 8; ++r)
#pragma unroll
    for (int c = 0; c < 8; ++c) acc[r][c] = 0.f;

#pragma unroll 4
  for (int k = 0; k < 128; ++k) {
    float4 a0 = *(const float4*)&xs[k][rg * 8];
    float4 a1 = *(const float4*)&xs[k][rg * 8 + 4];
    float4 b0 = *(const float4*)&ws[k][cg * 8];
    float4 b1 = *(const float4*)&ws[k][cg * 8 + 4];
    float xv[8] = {a0.x, a0.y, a0.z, a0.w, a1.x, a1.y, a1.z, a1.w};
    float wv[8] = {b0.x, b0.y, b0.z, b0.w, b1.x, b1.y, b1.z, b1.w};
#pragma unroll
    for (int r = 0; r < 8; ++r)
#pragma unroll
      for (int c = 0; c < 8; ++c) acc[r][c] += xv[r] * wv[c];
  }

#pragma unroll
  for (int r = 0; r < 8; ++r) {
    const int grow = row0 + rg * 8 + r;
    if (grow < N) {
      float4* dst = (float4*)(proj + (size_t)grow * HC + cg * 8);
      dst[0] = make_float4(acc[r][0], acc[r][1], acc[r][2], acc[r][3]);
      dst[1] = make_float4(acc[r][4], acc[r][5], acc[r][6], acc[r][7]);
    }
  }
}

// histogram over exact destination node
__global__ __launch_bounds__(256) void edge_hist(const int* __restrict__ ecol,
                                                 int* __restrict__ hist, int E) {
  const int i = blockIdx.x * 256 + threadIdx.x;
  if (i < E) atomicAdd(&hist[ecol[i]], 1);
}

// --- hierarchical exclusive scan over nb counters ---
__device__ __forceinline__ int block_scan_excl(int tsum, int* ls, int tid, int* total) {
  ls[tid] = tsum;
  __syncthreads();
  for (int off = 1; off < 256; off <<= 1) {
    int v = (tid >= off) ? ls[tid - off] : 0;
    __syncthreads();
    ls[tid] += v;
    __syncthreads();
  }
  *total = ls[255];
  return ls[tid] - tsum;
}

__global__ __launch_bounds__(256) void k_scan_a(const int* __restrict__ hist,
                                                int* __restrict__ sums, int nb) {
  __shared__ int ls[256];
  const int tid = threadIdx.x;
  const int base = blockIdx.x * CHUNK + tid * 8;
  int t = 0;
#pragma unroll
  for (int j = 0; j < 8; ++j) { const int i = base + j; if (i < nb) t += hist[i]; }
  int total;
  block_scan_excl(t, ls, tid, &total);
  if (tid == 0) sums[blockIdx.x] = total;
}

__global__ __launch_bounds__(256) void k_scan_b(int* __restrict__ sums, int nc,
                                                int* __restrict__ starts,
                                                int* __restrict__ cursor, int nb) {
  __shared__ int ls[256];
  const int tid = threadIdx.x;
  const int t = (tid < nc) ? sums[tid] : 0;
  int total;
  const int excl = block_scan_excl(t, ls, tid, &total);
  if (tid < nc) sums[tid] = excl;
  if (tid == 0) { starts[nb] = total; cursor[nb] = total; }
}

__global__ __launch_bounds__(256) void k_scan_c(const int* __restrict__ hist,
                                                const int* __restrict__ sums,
                                                int* __restrict__ starts,
                                                int* __restrict__ cursor, int nb) {
  __shared__ int ls[256];
  const int tid = threadIdx.x;
  const int base = blockIdx.x * CHUNK + tid * 8;
  int t = 0;
#pragma unroll
  for (int j = 0; j < 8; ++j) { const int i = base + j; if (i < nb) t += hist[i]; }
  int total;
  const int excl = block_scan_excl(t, ls, tid, &total);
  int run = sums[blockIdx.x] + excl;
#pragma unroll
  for (int j = 0; j < 8; ++j) {
    const int i = base + j;
    if (i < nb) { starts[i] = run; cursor[i] = run; run += hist[i]; }
  }
}

// CSR permutation: rc[p] = src row, records grouped by dst node.
__global__ __launch_bounds__(256) void scatter_rc(const int* __restrict__ erow,
                                                  const int* __restrict__ ecol,
                                                  int* __restrict__ cursor,
                                                  int* __restrict__ rc, int E) {
  const int i = blockIdx.x * 256 + threadIdx.x;
  if (i < E) {
    const int p = atomicAdd(&cursor[ecol[i]], 1);
    rc[p] = erow[i];
  }
}

// Wave per dst node, HALF-WAVE per edge: lane l (0..31) owns float4 of channels
// 4l..4l+3 (head = l>>3), so the wave processes 2 edges/iteration. Score reduce
// is 4 in-lane FMAs + 3 shuffle levels (within 8 lanes). Stabilizer = analytic
// bound M0_h = sum|att[h]| (cancels in the ratio); true per-head max tracked via
// direct global atomicMax so fix_clamp can reproduce max(norm,1e-12) exactly.
__global__ __launch_bounds__(256) void fused_apply(const float* __restrict__ proj,
                                                   const int* __restrict__ rc,
                                                   const int* __restrict__ starts,
                                                   const float* __restrict__ att,
                                                   float* __restrict__ out,
                                                   float* __restrict__ den,
                                                   unsigned* __restrict__ headmax_u, int N) {
  __shared__ unsigned blkmax[HEADS];
  const int tid = threadIdx.x;
  if (tid < HEADS) blkmax[tid] = 0u;
  __syncthreads();
  const int lane = tid & 63;
  const int half = lane >> 5;
  const int l = lane & 31;
  const int c0 = l * 4;
  const int head = l >> 3;
  const int n = blockIdx.x * 4 + (tid >> 6);
  float lm = -3.0e38f;

  if (n < N) {
    const float4 a4 = ((const float4*)att)[l];
    float M0 = fabsf(a4.x) + fabsf(a4.y) + fabsf(a4.z) + fabsf(a4.w);
    M0 += __shfl_xor(M0, 4, 64);
    M0 += __shfl_xor(M0, 2, 64);
    M0 += __shfl_xor(M0, 1, 64);
    const float4 d4 = *(const float4*)(proj + (size_t)n * HC + c0);
    const int beg = starts[n];
    const int end = starts[n + 1];

    float ax = 0.f, ay = 0.f, az = 0.f, aw = 0.f, dsum = 0.f;
    int i = beg;
    for (; i + 4 <= end; i += 4) {
      const int rowA = rc[i + half];
      const int rowB = rc[i + 2 + half];
      const float4 sA = *(const float4*)(proj + (size_t)rowA * HC + c0);
      const float4 sB = *(const float4*)(proj + (size_t)rowB * HC + c0);
      float pA = fast_tanh(sA.x + d4.x) * a4.x;
      float pB = fast_tanh(sB.x + d4.x) * a4.x;
      pA += fast_tanh(sA.y + d4.y) * a4.y;
      pB += fast_tanh(sB.y + d4.y) * a4.y;
      pA += fast_tanh(sA.z + d4.z) * a4.z;
      pB += fast_tanh(sB.z + d4.z) * a4.z;
      pA += fast_tanh(sA.w + d4.w) * a4.w;
      pB += fast_tanh(sB.w + d4.w) * a4.w;
      pA += __shfl_xor(pA, 4, 64);  pB += __shfl_xor(pB, 4, 64);
      pA += __shfl_xor(pA, 2, 64);  pB += __shfl_xor(pB, 2, 64);
      pA += __shfl_xor(pA, 1, 64);  pB += __shfl_xor(pB, 1, 64);
      lm = fmaxf(lm, fmaxf(pA, pB));
      const float eA = __expf(pA - M0);
      const float eB = __expf(pB - M0);
      ax += sA.x * eA + sB.x * eB;
      ay += sA.y * eA + sB.y * eB;
      az += sA.z * eA + sB.z * eB;
      aw += sA.w * eA + sB.w * eB;
      dsum += eA + eB;
    }
    for (; i < end; i += 2) {
      const int idx = i + half;
      const bool valid = idx < end;
      const int row = rc[valid ? idx : i];
      const float4 s4 = *(const float4*)(proj + (size_t)row * HC + c0);
      float p = fast_tanh(s4.x + d4.x) * a4.x
              + fast_tanh(s4.y + d4.y) * a4.y
              + fast_tanh(s4.z + d4.z) * a4.z
              + fast_tanh(s4.w + d4.w) * a4.w;
      p += __shfl_xor(p, 4, 64);
      p += __shfl_xor(p, 2, 64);
      p += __shfl_xor(p, 1, 64);
      if (!valid) p = -3.0e38f;
      lm = fmaxf(lm, p);
      const float e = __expf(p - M0);
      ax += s4.x * e; ay += s4.y * e; az += s4.z * e; aw += s4.w * e;
      dsum += e;
    }
    // merge halves
    dsum += __shfl_xor(dsum, 32, 64);
    ax += __shfl_xor(ax, 32, 64);
    ay += __shfl_xor(ay, 32, 64);
    az += __shfl_xor(az, 32, 64);
    aw += __shfl_xor(aw, 32, 64);
    lm = fmaxf(lm, __shfl_xor(lm, 32, 64));
    if (half == 0) {
      const float inv = 1.f / fmaxf(dsum, 1e-38f);
      *(float4*)(out + (size_t)n * HC + c0) =
          make_float4(ax * inv, ay * inv, az * inv, aw * inv);
      if ((l & 7) == 0) den[n * HEADS + head] = dsum;
      if ((l & 7) == 0) atomicMax(&blkmax[head], flip_f32(lm));
    }
  }
  __syncthreads();
  if (tid < HEADS) atomicMax(&headmax_u[tid], blkmax[tid]);
}

// Reference normalizer = den * exp(M0_h - Mt_h). If below 1e-12 the reference
// clamps: out_ref = out_ours * (ref_den / 1e-12). Apply that correction.
__global__ __launch_bounds__(256) void fix_clamp(float* __restrict__ out,
                                                 const float* __restrict__ den,
                                                 const unsigned* __restrict__ headmax_u,
                                                 const float* __restrict__ att, int N) {
  const int t = blockIdx.x * 256 + threadIdx.x;
  if (t >= N * HEADS) return;
  const int n = t >> 2;
  const int h = t & 3;
  float M0 = 0.f;
#pragma unroll
  for (int c = 0; c < OUT_CH; ++c) M0 += fabsf(att[h * OUT_CH + c]);
  const float Mt = unflip_f32(headmax_u[h]);
  const float f = den[t] * __expf(M0 - Mt);
  if (f < 1e-12f) {
    const float s = f * 1e12f;
    float4* p = (float4*)(out + (size_t)n * HC + h * OUT_CH);
#pragma unroll
    for (int j = 0; j < 8; ++j) {
      float4 v = p[j];
      v.x *= s; v.y *= s; v.z *= s; v.w *= s;
      p[j] = v;
    }
  }
}

// blockmax -> corr (fallback path only)
__global__ __launch_bounds__(256) void reduce_corr(const unsigned* __restrict__ blockmax,
                                                   const float* __restrict__ att,
                                                   float* __restrict__ corr, int nblk) {
  __shared__ unsigned sm[HEADS];
  const int tid = threadIdx.x;
  if (tid < HEADS) sm[tid] = 0u;
  __syncthreads();
  const int h = tid & 3;
  unsigned k = 0u;
  for (int i = tid >> 2; i < nblk; i += 64) k = max(k, blockmax[i * HEADS + h]);
  atomicMax(&sm[h], k);
  __syncthreads();
  if (tid < HEADS) {
    const float Mt = unflip_f32(sm[tid]);
    float M0 = 0.f;
#pragma unroll
    for (int c = 0; c < OUT_CH; ++c) M0 += fabsf(att[tid * OUT_CH + c]);
    corr[tid] = __expf(M0 - Mt);
    corr[4 + tid] = Mt;
  }
}

// --- fallback path (ws too small): score-max pass + edge-parallel atomics ---
__global__ __launch_bounds__(256) void score_max(const float* __restrict__ proj,
                                                 const int* __restrict__ erow,
                                                 const int* __restrict__ ecol,
                                                 const float* __restrict__ att,
                                                 unsigned* __restrict__ blockmax, int E) {
  __shared__ unsigned blkmax[HEADS];
  const int tid = threadIdx.x;
  if (tid < HEADS) blkmax[tid] = 0u;
  __syncthreads();
  const int lane = tid & 63;
  const int wid = tid >> 6;
  const float a0 = att[lane];
  const float a1 = att[lane + 64];
  float lmA = -3.0e38f, lmB = -3.0e38f;
  const int stride = SCORE_BLOCKS * 16;

  for (int base = (blockIdx.x * 4 + wid) * 4; base < E; base += stride) {
    const int bu = __builtin_amdgcn_readfirstlane(base);
    const int lim = min(bu + 4, E);
    for (int e = bu; e < lim; ++e) {
      const int r0 = erow[e], c0 = ecol[e];
      const float* ps = proj + (size_t)r0 * HC;
      const float* pd = proj + (size_t)c0 * HC;
      float pA = fast_tanh(ps[lane] + pd[lane]) * a0;
      float pB = fast_tanh(ps[lane + 64] + pd[lane + 64]) * a1;
#pragma unroll
      for (int m = 16; m >= 1; m >>= 1) {
        pA += __shfl_xor(pA, m, 64);
        pB += __shfl_xor(pB, m, 64);
      }
      lmA = fmaxf(lmA, pA);
      lmB = fmaxf(lmB, pB);
    }
  }
  if ((lane & 31) == 0) {
    const int hh = lane >> 5;
    atomicMax(&blkmax[hh], flip_f32(lmA));
    atomicMax(&blkmax[hh + 2], flip_f32(lmB));
  }
  __syncthreads();
  if (tid < HEADS) blockmax[blockIdx.x * HEADS + tid] = blkmax[tid];
}

__global__ __launch_bounds__(256) void edge_apply_fb(const float* __restrict__ proj,
                                                     const int* __restrict__ erow,
                                                     const int* __restrict__ ecol,
                                                     const float* __restrict__ att,
                                                     const float* __restrict__ headmax,
                                                     float* __restrict__ out,
                                                     float* __restrict__ norm, int E) {
  const int tid = threadIdx.x;
  const int e = blockIdx.x * 2 + (tid >> 7);
  if (e >= E) return;
  const int ch = tid & 127;
  const int h = ch >> 5;
  const float M = headmax[h];
  const int row = erow[e];
  const int col = ecol[e];
  const float sv = proj[(size_t)row * HC + ch];
  const float dv = proj[(size_t)col * HC + ch];
  float p = fast_tanh(sv + dv) * att[ch];
#pragma unroll
  for (int m = 16; m >= 1; m >>= 1) p += __shfl_xor(p, m, 64);
  const float w = __expf(p - M);
  unsafeAtomicAdd(&out[(size_t)col * HC + ch], sv * w);
  if ((ch & 31) == 0) unsafeAtomicAdd(&norm[(size_t)col * HEADS + h], w);
}

__global__ __launch_bounds__(256) void finalize_fb(float* __restrict__ out,
                                                   const float* __restrict__ norm, int N) {
  const int idx = blockIdx.x * blockDim.x + threadIdx.x;
  const int total = N * (HC / 4);
  if (idx >= total) return;
  const int base = idx * 4;
  const int node = base >> 7;
  const int h = (base >> 5) & 3;
  const float inv = 1.f / fmaxf(norm[node * HEADS + h], 1e-12f);
  float4 v = ((float4*)out)[idx];
  v.x *= inv; v.y *= inv; v.z *= inv; v.w *= inv;
  ((float4*)out)[idx] = v;
}

extern "C" void kernel_launch(void* const* d_in, const int* in_sizes, int n_in,
                              void* d_out, int out_size, void* d_ws, size_t ws_size,
                              hipStream_t stream) {
  const float* x    = (const float*)d_in[0];
  const int*   eidx = (const int*)d_in[1];  // [2][E]: row(src) then col(dst)
  const float* W    = (const float*)d_in[2];
  const float* att  = (const float*)d_in[3];
  float* out = (float*)d_out;

  const int N = in_sizes[0] / IN_CH;
  const int E = in_sizes[1] / 2;
  const int nb = N;
  const int nc = (nb + CHUNK - 1) / CHUNK;  // scan chunks (<=256 supported)

  // ws layout (16B-aligned pieces)
  char* p = (char*)d_ws;
  float* proj = (float*)p;  p += (size_t)N * HC * 4;
  int* rc = (int*)p;        p += (((size_t)E * 4 + 15) & ~15ull);
  float* den = (float*)p;   p += (((size_t)N * HEADS * 4 + 15) & ~15ull);
  int* hist = (int*)p;      p += (((size_t)(nb + 4) * 4 + 15) & ~15ull);  // +4: headmax_u
  int* starts = (int*)p;    p += (((size_t)(nb + 1) * 4 + 15) & ~15ull);
  int* cursor = (int*)p;    p += (((size_t)(nb + 1) * 4 + 15) & ~15ull);
  int* sums = (int*)p;      p += 1024;
  unsigned* headmax_u = (unsigned*)(hist + nb);
  const size_t need_full = (size_t)(p - (char*)d_ws);
  const bool full = (ws_size >= need_full) && (nc <= 256);

  gemm_xW<<<(N + 127) / 128, 256, 0, stream>>>(x, W, proj, N);

  if (full) {
    hipMemsetAsync(hist, 0, (size_t)(nb + 4) * sizeof(int), stream);  // hist + headmax_u
    edge_hist<<<(E + 255) / 256, 256, 0, stream>>>(eidx + E, hist, E);
    k_scan_a<<<nc, 256, 0, stream>>>(hist, sums, nb);
    k_scan_b<<<1, 256, 0, stream>>>(sums, nc, starts, cursor, nb);
    k_scan_c<<<nc, 256, 0, stream>>>(hist, sums, starts, cursor, nb);
    scatter_rc<<<(E + 255) / 256, 256, 0, stream>>>(eidx, eidx + E, cursor, rc, E);
    fused_apply<<<(N + 3) / 4, 256, 0, stream>>>(proj, rc, starts, att, out, den,
                                                 headmax_u, N);
    fix_clamp<<<(N * HEADS + 255) / 256, 256, 0, stream>>>(out, den, headmax_u, att, N);
  } else {
    // minimal-ws fallback: blockmax/corr/norm packed right after proj
    unsigned* bm = (unsigned*)(proj + (size_t)N * HC);
    float* cr = (float*)(bm + SCORE_BLOCKS * HEADS);
    float* norm = cr + 8;
    hipMemsetAsync(out, 0, (size_t)out_size * sizeof(float), stream);
    hipMemsetAsync(norm, 0, (size_t)N * HEADS * sizeof(float), stream);
    score_max<<<SCORE_BLOCKS, 256, 0, stream>>>(proj, eidx, eidx + E, att, bm, E);
    reduce_corr<<<1, 256, 0, stream>>>(bm, att, cr, SCORE_BLOCKS);
    edge_apply_fb<<<(E + 1) / 2, 256, 0, stream>>>(proj, eidx, eidx + E, att, cr + 4, out, norm, E);
    finalize_fb<<<(N * (HC / 4) + 255) / 256, 256, 0, stream>>>(out, norm, N);
  }
}

// Round 4
// 515.161 us; speedup vs baseline: 1.3176x; 1.3176x over previous
//
#include <hip/hip_runtime.h>

#define IN_CH 128
#define HEADS 4
#define OUT_CH 32
#define HC 128           // HEADS*OUT_CH
#define SCORE_BLOCKS 4096
#define CHUNK 2048       // scan chunk (256 thr x 8)

__device__ __forceinline__ unsigned flip_f32(float x) {
  unsigned u = __float_as_uint(x);
  return (u & 0x80000000u) ? ~u : (u | 0x80000000u);
}
__device__ __forceinline__ float unflip_f32(unsigned k) {
  unsigned u = (k & 0x80000000u) ? (k ^ 0x80000000u) : ~k;
  return __uint_as_float(u);
}
__device__ __forceinline__ float fast_tanh(float x) {
  return 1.f - 2.f / (__expf(2.f * x) + 1.f);
}

// proj[N][128] = x[N][128] @ W[128][128]
__global__ __launch_bounds__(256) void gemm_xW(const float* __restrict__ x,
                                               const float* __restrict__ W,
                                               float* __restrict__ proj, int N) {
  __shared__ float xs[128][132];
  __shared__ float ws[128][128];
  const int tid = threadIdx.x;
  const int row0 = blockIdx.x * 128;

  {
    const float4* Wv = (const float4*)W;
    float4* wsv = (float4*)ws;
#pragma unroll
    for (int i = 0; i < 16; ++i) wsv[i * 256 + tid] = Wv[i * 256 + tid];
  }
  {
    const int r = tid >> 1;
    const int k0 = (tid & 1) * 64;
    const int grow = row0 + r;
    const bool valid = grow < N;
    const float4* src = (const float4*)(x + (size_t)grow * IN_CH + k0);
#pragma unroll
    for (int i = 0; i < 16; ++i) {
      float4 v = valid ? src[i] : make_float4(0.f, 0.f, 0.f, 0.f);
      const int k = k0 + i * 4;
      xs[k][r] = v.x; xs[k + 1][r] = v.y; xs[k + 2][r] = v.z; xs[k + 3][r] = v.w;
    }
  }
  __syncthreads();

  const int cg = tid & 15;
  const int rg = tid >> 4;
  float acc[8][8];
#pragma unroll
  for (int r = 0; r < 8; ++r)
#pragma unroll
    for (int c = 0; c < 8; ++c) acc[r][c] = 0.f;

#pragma unroll 4
  for (int k = 0; k < 128; ++k) {
    float4 a0 = *(const float4*)&xs[k][rg * 8];
    float4 a1 = *(const float4*)&xs[k][rg * 8 + 4];
    float4 b0 = *(const float4*)&ws[k][cg * 8];
    float4 b1 = *(const float4*)&ws[k][cg * 8 + 4];
    float xv[8] = {a0.x, a0.y, a0.z, a0.w, a1.x, a1.y, a1.z, a1.w};
    float wv[8] = {b0.x, b0.y, b0.z, b0.w, b1.x, b1.y, b1.z, b1.w};
#pragma unroll
    for (int r = 0; r < 8; ++r)
#pragma unroll
      for (int c = 0; c < 8; ++c) acc[r][c] += xv[r] * wv[c];
  }

#pragma unroll
  for (int r = 0; r < 8; ++r) {
    const int grow = row0 + rg * 8 + r;
    if (grow < N) {
      float4* dst = (float4*)(proj + (size_t)grow * HC + cg * 8);
      dst[0] = make_float4(acc[r][0], acc[r][1], acc[r][2], acc[r][3]);
      dst[1] = make_float4(acc[r][4], acc[r][5], acc[r][6], acc[r][7]);
    }
  }
}

// histogram over exact destination node
__global__ __launch_bounds__(256) void edge_hist(const int* __restrict__ ecol,
                                                 int* __restrict__ hist, int E) {
  const int i = blockIdx.x * 256 + threadIdx.x;
  if (i < E) atomicAdd(&hist[ecol[i]], 1);
}

// --- hierarchical exclusive scan over nb counters ---
__device__ __forceinline__ int block_scan_excl(int tsum, int* ls, int tid, int* total) {
  ls[tid] = tsum;
  __syncthreads();
  for (int off = 1; off < 256; off <<= 1) {
    int v = (tid >= off) ? ls[tid - off] : 0;
    __syncthreads();
    ls[tid] += v;
    __syncthreads();
  }
  *total = ls[255];
  return ls[tid] - tsum;
}

__global__ __launch_bounds__(256) void k_scan_a(const int* __restrict__ hist,
                                                int* __restrict__ sums, int nb) {
  __shared__ int ls[256];
  const int tid = threadIdx.x;
  const int base = blockIdx.x * CHUNK + tid * 8;
  int t = 0;
#pragma unroll
  for (int j = 0; j < 8; ++j) { const int i = base + j; if (i < nb) t += hist[i]; }
  int total;
  block_scan_excl(t, ls, tid, &total);
  if (tid == 0) sums[blockIdx.x] = total;
}

__global__ __launch_bounds__(256) void k_scan_b(int* __restrict__ sums, int nc,
                                                int* __restrict__ starts,
                                                int* __restrict__ cursor, int nb) {
  __shared__ int ls[256];
  const int tid = threadIdx.x;
  const int t = (tid < nc) ? sums[tid] : 0;
  int total;
  const int excl = block_scan_excl(t, ls, tid, &total);
  if (tid < nc) sums[tid] = excl;
  if (tid == 0) { starts[nb] = total; cursor[nb] = total; }
}

__global__ __launch_bounds__(256) void k_scan_c(const int* __restrict__ hist,
                                                const int* __restrict__ sums,
                                                int* __restrict__ starts,
                                                int* __restrict__ cursor, int nb) {
  __shared__ int ls[256];
  const int tid = threadIdx.x;
  const int base = blockIdx.x * CHUNK + tid * 8;
  int t = 0;
#pragma unroll
  for (int j = 0; j < 8; ++j) { const int i = base + j; if (i < nb) t += hist[i]; }
  int total;
  const int excl = block_scan_excl(t, ls, tid, &total);
  int run = sums[blockIdx.x] + excl;
#pragma unroll
  for (int j = 0; j < 8; ++j) {
    const int i = base + j;
    if (i < nb) { starts[i] = run; cursor[i] = run; run += hist[i]; }
  }
}

// CSR permutation: rc[p] = src row, records grouped by dst node.
__global__ __launch_bounds__(256) void scatter_rc(const int* __restrict__ erow,
                                                  const int* __restrict__ ecol,
                                                  int* __restrict__ cursor,
                                                  int* __restrict__ rc, int E) {
  const int i = blockIdx.x * 256 + threadIdx.x;
  if (i < E) {
    const int p = atomicAdd(&cursor[ecol[i]], 1);
    rc[p] = erow[i];
  }
}

// Wave per dst node, HALF-WAVE per edge, 8-edge main unroll: lane l (0..31)
// owns float4 of channels 4l..4l+3 (head = l>>3). Per main iteration each lane
// issues 4 independent dwordx4 gathers (MLP) then 16 independent tanh chains
// (VALU ILP). Stabilizer = analytic bound M0_h = sum|att[h]| (cancels in the
// ratio); true per-head max tracked so fix_clamp reproduces max(norm,1e-12).
__global__ __launch_bounds__(256) void fused_apply(const float* __restrict__ proj,
                                                   const int* __restrict__ rc,
                                                   const int* __restrict__ starts,
                                                   const float* __restrict__ att,
                                                   float* __restrict__ out,
                                                   float* __restrict__ den,
                                                   unsigned* __restrict__ headmax_u, int N) {
  __shared__ unsigned blkmax[HEADS];
  const int tid = threadIdx.x;
  if (tid < HEADS) blkmax[tid] = 0u;
  __syncthreads();
  const int lane = tid & 63;
  const int half = lane >> 5;
  const int l = lane & 31;
  const int c0 = l * 4;
  const int head = l >> 3;
  const int n = blockIdx.x * 4 + (tid >> 6);
  float lm = -3.0e38f;

  if (n < N) {
    const float4 a4 = ((const float4*)att)[l];
    float M0 = fabsf(a4.x) + fabsf(a4.y) + fabsf(a4.z) + fabsf(a4.w);
    M0 += __shfl_xor(M0, 4, 64);
    M0 += __shfl_xor(M0, 2, 64);
    M0 += __shfl_xor(M0, 1, 64);
    const float4 d4 = *(const float4*)(proj + (size_t)n * HC + c0);
    const int beg = __builtin_amdgcn_readfirstlane(starts[n]);
    const int end = __builtin_amdgcn_readfirstlane(starts[n + 1]);

    float ax = 0.f, ay = 0.f, az = 0.f, aw = 0.f, dsum = 0.f;
    int i = beg;
    // main: 8 edges/iteration (4 per half-wave) -> 4 gathers in flight/lane
    for (; i + 8 <= end; i += 8) {
      const int r0 = rc[i + half];
      const int r1 = rc[i + 2 + half];
      const int r2 = rc[i + 4 + half];
      const int r3 = rc[i + 6 + half];
      const float4 s0 = *(const float4*)(proj + (size_t)r0 * HC + c0);
      const float4 s1 = *(const float4*)(proj + (size_t)r1 * HC + c0);
      const float4 s2 = *(const float4*)(proj + (size_t)r2 * HC + c0);
      const float4 s3 = *(const float4*)(proj + (size_t)r3 * HC + c0);
      float p0 = fast_tanh(s0.x + d4.x) * a4.x + fast_tanh(s0.y + d4.y) * a4.y
               + fast_tanh(s0.z + d4.z) * a4.z + fast_tanh(s0.w + d4.w) * a4.w;
      float p1 = fast_tanh(s1.x + d4.x) * a4.x + fast_tanh(s1.y + d4.y) * a4.y
               + fast_tanh(s1.z + d4.z) * a4.z + fast_tanh(s1.w + d4.w) * a4.w;
      float p2 = fast_tanh(s2.x + d4.x) * a4.x + fast_tanh(s2.y + d4.y) * a4.y
               + fast_tanh(s2.z + d4.z) * a4.z + fast_tanh(s2.w + d4.w) * a4.w;
      float p3 = fast_tanh(s3.x + d4.x) * a4.x + fast_tanh(s3.y + d4.y) * a4.y
               + fast_tanh(s3.z + d4.z) * a4.z + fast_tanh(s3.w + d4.w) * a4.w;
      p0 += __shfl_xor(p0, 4, 64);  p1 += __shfl_xor(p1, 4, 64);
      p2 += __shfl_xor(p2, 4, 64);  p3 += __shfl_xor(p3, 4, 64);
      p0 += __shfl_xor(p0, 2, 64);  p1 += __shfl_xor(p1, 2, 64);
      p2 += __shfl_xor(p2, 2, 64);  p3 += __shfl_xor(p3, 2, 64);
      p0 += __shfl_xor(p0, 1, 64);  p1 += __shfl_xor(p1, 1, 64);
      p2 += __shfl_xor(p2, 1, 64);  p3 += __shfl_xor(p3, 1, 64);
      lm = fmaxf(lm, fmaxf(fmaxf(p0, p1), fmaxf(p2, p3)));
      const float e0 = __expf(p0 - M0);
      const float e1 = __expf(p1 - M0);
      const float e2 = __expf(p2 - M0);
      const float e3 = __expf(p3 - M0);
      ax += s0.x * e0 + s1.x * e1 + s2.x * e2 + s3.x * e3;
      ay += s0.y * e0 + s1.y * e1 + s2.y * e2 + s3.y * e3;
      az += s0.z * e0 + s1.z * e1 + s2.z * e2 + s3.z * e3;
      aw += s0.w * e0 + s1.w * e1 + s2.w * e2 + s3.w * e3;
      dsum += (e0 + e1) + (e2 + e3);
    }
    // middle: one 4-edge step
    if (i + 4 <= end) {
      const int r0 = rc[i + half];
      const int r1 = rc[i + 2 + half];
      const float4 s0 = *(const float4*)(proj + (size_t)r0 * HC + c0);
      const float4 s1 = *(const float4*)(proj + (size_t)r1 * HC + c0);
      float p0 = fast_tanh(s0.x + d4.x) * a4.x + fast_tanh(s0.y + d4.y) * a4.y
               + fast_tanh(s0.z + d4.z) * a4.z + fast_tanh(s0.w + d4.w) * a4.w;
      float p1 = fast_tanh(s1.x + d4.x) * a4.x + fast_tanh(s1.y + d4.y) * a4.y
               + fast_tanh(s1.z + d4.z) * a4.z + fast_tanh(s1.w + d4.w) * a4.w;
      p0 += __shfl_xor(p0, 4, 64);  p1 += __shfl_xor(p1, 4, 64);
      p0 += __shfl_xor(p0, 2, 64);  p1 += __shfl_xor(p1, 2, 64);
      p0 += __shfl_xor(p0, 1, 64);  p1 += __shfl_xor(p1, 1, 64);
      lm = fmaxf(lm, fmaxf(p0, p1));
      const float e0 = __expf(p0 - M0);
      const float e1 = __expf(p1 - M0);
      ax += s0.x * e0 + s1.x * e1;
      ay += s0.y * e0 + s1.y * e1;
      az += s0.z * e0 + s1.z * e1;
      aw += s0.w * e0 + s1.w * e1;
      dsum += e0 + e1;
      i += 4;
    }
    // tail: 2 edges/iteration, masked
    for (; i < end; i += 2) {
      const int idx = i + half;
      const bool valid = idx < end;
      const int row = rc[valid ? idx : i];
      const float4 s4 = *(const float4*)(proj + (size_t)row * HC + c0);
      float p = fast_tanh(s4.x + d4.x) * a4.x
              + fast_tanh(s4.y + d4.y) * a4.y
              + fast_tanh(s4.z + d4.z) * a4.z
              + fast_tanh(s4.w + d4.w) * a4.w;
      p += __shfl_xor(p, 4, 64);
      p += __shfl_xor(p, 2, 64);
      p += __shfl_xor(p, 1, 64);
      if (!valid) p = -3.0e38f;
      lm = fmaxf(lm, p);
      const float e = __expf(p - M0);
      ax += s4.x * e; ay += s4.y * e; az += s4.z * e; aw += s4.w * e;
      dsum += e;
    }
    // merge halves
    dsum += __shfl_xor(dsum, 32, 64);
    ax += __shfl_xor(ax, 32, 64);
    ay += __shfl_xor(ay, 32, 64);
    az += __shfl_xor(az, 32, 64);
    aw += __shfl_xor(aw, 32, 64);
    lm = fmaxf(lm, __shfl_xor(lm, 32, 64));
    if (half == 0) {
      const float inv = 1.f / fmaxf(dsum, 1e-38f);
      *(float4*)(out + (size_t)n * HC + c0) =
          make_float4(ax * inv, ay * inv, az * inv, aw * inv);
      if ((l & 7) == 0) den[n * HEADS + head] = dsum;
      if ((l & 7) == 0) atomicMax(&blkmax[head], flip_f32(lm));
    }
  }
  __syncthreads();
  if (tid < HEADS) {
    const unsigned v = blkmax[tid];
    if (v > headmax_u[tid]) atomicMax(&headmax_u[tid], v);
  }
}

// Reference normalizer = den * exp(M0_h - Mt_h). If below 1e-12 the reference
// clamps: out_ref = out_ours * (ref_den / 1e-12). Apply that correction.
__global__ __launch_bounds__(256) void fix_clamp(float* __restrict__ out,
                                                 const float* __restrict__ den,
                                                 const unsigned* __restrict__ headmax_u,
                                                 const float* __restrict__ att, int N) {
  const int t = blockIdx.x * 256 + threadIdx.x;
  if (t >= N * HEADS) return;
  const int n = t >> 2;
  const int h = t & 3;
  float M0 = 0.f;
#pragma unroll
  for (int c = 0; c < OUT_CH; ++c) M0 += fabsf(att[h * OUT_CH + c]);
  const float Mt = unflip_f32(headmax_u[h]);
  const float f = den[t] * __expf(M0 - Mt);
  if (f < 1e-12f) {
    const float s = f * 1e12f;
    float4* p = (float4*)(out + (size_t)n * HC + h * OUT_CH);
#pragma unroll
    for (int j = 0; j < 8; ++j) {
      float4 v = p[j];
      v.x *= s; v.y *= s; v.z *= s; v.w *= s;
      p[j] = v;
    }
  }
}

// blockmax -> corr (fallback path only)
__global__ __launch_bounds__(256) void reduce_corr(const unsigned* __restrict__ blockmax,
                                                   const float* __restrict__ att,
                                                   float* __restrict__ corr, int nblk) {
  __shared__ unsigned sm[HEADS];
  const int tid = threadIdx.x;
  if (tid < HEADS) sm[tid] = 0u;
  __syncthreads();
  const int h = tid & 3;
  unsigned k = 0u;
  for (int i = tid >> 2; i < nblk; i += 64) k = max(k, blockmax[i * HEADS + h]);
  atomicMax(&sm[h], k);
  __syncthreads();
  if (tid < HEADS) {
    const float Mt = unflip_f32(sm[tid]);
    float M0 = 0.f;
#pragma unroll
    for (int c = 0; c < OUT_CH; ++c) M0 += fabsf(att[tid * OUT_CH + c]);
    corr[tid] = __expf(M0 - Mt);
    corr[4 + tid] = Mt;
  }
}

// --- fallback path (ws too small): score-max pass + edge-parallel atomics ---
__global__ __launch_bounds__(256) void score_max(const float* __restrict__ proj,
                                                 const int* __restrict__ erow,
                                                 const int* __restrict__ ecol,
                                                 const float* __restrict__ att,
                                                 unsigned* __restrict__ blockmax, int E) {
  __shared__ unsigned blkmax[HEADS];
  const int tid = threadIdx.x;
  if (tid < HEADS) blkmax[tid] = 0u;
  __syncthreads();
  const int lane = tid & 63;
  const int wid = tid >> 6;
  const float a0 = att[lane];
  const float a1 = att[lane + 64];
  float lmA = -3.0e38f, lmB = -3.0e38f;
  const int stride = SCORE_BLOCKS * 16;

  for (int base = (blockIdx.x * 4 + wid) * 4; base < E; base += stride) {
    const int bu = __builtin_amdgcn_readfirstlane(base);
    const int lim = min(bu + 4, E);
    for (int e = bu; e < lim; ++e) {
      const int r0 = erow[e], c0 = ecol[e];
      const float* ps = proj + (size_t)r0 * HC;
      const float* pd = proj + (size_t)c0 * HC;
      float pA = fast_tanh(ps[lane] + pd[lane]) * a0;
      float pB = fast_tanh(ps[lane + 64] + pd[lane + 64]) * a1;
#pragma unroll
      for (int m = 16; m >= 1; m >>= 1) {
        pA += __shfl_xor(pA, m, 64);
        pB += __shfl_xor(pB, m, 64);
      }
      lmA = fmaxf(lmA, pA);
      lmB = fmaxf(lmB, pB);
    }
  }
  if ((lane & 31) == 0) {
    const int hh = lane >> 5;
    atomicMax(&blkmax[hh], flip_f32(lmA));
    atomicMax(&blkmax[hh + 2], flip_f32(lmB));
  }
  __syncthreads();
  if (tid < HEADS) blockmax[blockIdx.x * HEADS + tid] = blkmax[tid];
}

__global__ __launch_bounds__(256) void edge_apply_fb(const float* __restrict__ proj,
                                                     const int* __restrict__ erow,
                                                     const int* __restrict__ ecol,
                                                     const float* __restrict__ att,
                                                     const float* __restrict__ headmax,
                                                     float* __restrict__ out,
                                                     float* __restrict__ norm, int E) {
  const int tid = threadIdx.x;
  const int e = blockIdx.x * 2 + (tid >> 7);
  if (e >= E) return;
  const int ch = tid & 127;
  const int h = ch >> 5;
  const float M = headmax[h];
  const int row = erow[e];
  const int col = ecol[e];
  const float sv = proj[(size_t)row * HC + ch];
  const float dv = proj[(size_t)col * HC + ch];
  float p = fast_tanh(sv + dv) * att[ch];
#pragma unroll
  for (int m = 16; m >= 1; m >>= 1) p += __shfl_xor(p, m, 64);
  const float w = __expf(p - M);
  unsafeAtomicAdd(&out[(size_t)col * HC + ch], sv * w);
  if ((ch & 31) == 0) unsafeAtomicAdd(&norm[(size_t)col * HEADS + h], w);
}

__global__ __launch_bounds__(256) void finalize_fb(float* __restrict__ out,
                                                   const float* __restrict__ norm, int N) {
  const int idx = blockIdx.x * blockDim.x + threadIdx.x;
  const int total = N * (HC / 4);
  if (idx >= total) return;
  const int base = idx * 4;
  const int node = base >> 7;
  const int h = (base >> 5) & 3;
  const float inv = 1.f / fmaxf(norm[node * HEADS + h], 1e-12f);
  float4 v = ((float4*)out)[idx];
  v.x *= inv; v.y *= inv; v.z *= inv; v.w *= inv;
  ((float4*)out)[idx] = v;
}

extern "C" void kernel_launch(void* const* d_in, const int* in_sizes, int n_in,
                              void* d_out, int out_size, void* d_ws, size_t ws_size,
                              hipStream_t stream) {
  const float* x    = (const float*)d_in[0];
  const int*   eidx = (const int*)d_in[1];  // [2][E]: row(src) then col(dst)
  const float* W    = (const float*)d_in[2];
  const float* att  = (const float*)d_in[3];
  float* out = (float*)d_out;

  const int N = in_sizes[0] / IN_CH;
  const int E = in_sizes[1] / 2;
  const int nb = N;
  const int nc = (nb + CHUNK - 1) / CHUNK;  // scan chunks (<=256 supported)

  // ws layout (16B-aligned pieces)
  char* p = (char*)d_ws;
  float* proj = (float*)p;  p += (size_t)N * HC * 4;
  int* rc = (int*)p;        p += (((size_t)E * 4 + 15) & ~15ull);
  float* den = (float*)p;   p += (((size_t)N * HEADS * 4 + 15) & ~15ull);
  int* hist = (int*)p;      p += (((size_t)(nb + 4) * 4 + 15) & ~15ull);  // +4: headmax_u
  int* starts = (int*)p;    p += (((size_t)(nb + 1) * 4 + 15) & ~15ull);
  int* cursor = (int*)p;    p += (((size_t)(nb + 1) * 4 + 15) & ~15ull);
  int* sums = (int*)p;      p += 1024;
  unsigned* headmax_u = (unsigned*)(hist + nb);
  const size_t need_full = (size_t)(p - (char*)d_ws);
  const bool full = (ws_size >= need_full) && (nc <= 256);

  gemm_xW<<<(N + 127) / 128, 256, 0, stream>>>(x, W, proj, N);

  if (full) {
    hipMemsetAsync(hist, 0, (size_t)(nb + 4) * sizeof(int), stream);  // hist + headmax_u
    edge_hist<<<(E + 255) / 256, 256, 0, stream>>>(eidx + E, hist, E);
    k_scan_a<<<nc, 256, 0, stream>>>(hist, sums, nb);
    k_scan_b<<<1, 256, 0, stream>>>(sums, nc, starts, cursor, nb);
    k_scan_c<<<nc, 256, 0, stream>>>(hist, sums, starts, cursor, nb);
    scatter_rc<<<(E + 255) / 256, 256, 0, stream>>>(eidx, eidx + E, cursor, rc, E);
    fused_apply<<<(N + 3) / 4, 256, 0, stream>>>(proj, rc, starts, att, out, den,
                                                 headmax_u, N);
    fix_clamp<<<(N * HEADS + 255) / 256, 256, 0, stream>>>(out, den, headmax_u, att, N);
  } else {
    // minimal-ws fallback: blockmax/corr/norm packed right after proj
    unsigned* bm = (unsigned*)(proj + (size_t)N * HC);
    float* cr = (float*)(bm + SCORE_BLOCKS * HEADS);
    float* norm = cr + 8;
    hipMemsetAsync(out, 0, (size_t)out_size * sizeof(float), stream);
    hipMemsetAsync(norm, 0, (size_t)N * HEADS * sizeof(float), stream);
    score_max<<<SCORE_BLOCKS, 256, 0, stream>>>(proj, eidx, eidx + E, att, bm, E);
    reduce_corr<<<1, 256, 0, stream>>>(bm, att, cr, SCORE_BLOCKS);
    edge_apply_fb<<<(E + 1) / 2, 256, 0, stream>>>(proj, eidx, eidx + E, att, cr + 4, out, norm, E);
    finalize_fb<<<(N * (HC / 4) + 255) / 256, 256, 0, stream>>>(out, norm, N);
  }
}

// Round 5
// 514.740 us; speedup vs baseline: 1.3187x; 1.0008x over previous
//
#include <hip/hip_runtime.h>

#define IN_CH 128
#define HEADS 4
#define OUT_CH 32
#define HC 128           // HEADS*OUT_CH
#define SCORE_BLOCKS 4096
#define CHUNK 2048       // scan chunk (256 thr x 8)

__device__ __forceinline__ unsigned flip_f32(float x) {
  unsigned u = __float_as_uint(x);
  return (u & 0x80000000u) ? ~u : (u | 0x80000000u);
}
__device__ __forceinline__ float unflip_f32(unsigned k) {
  unsigned u = (k & 0x80000000u) ? (k ^ 0x80000000u) : ~k;
  return __uint_as_float(u);
}
__device__ __forceinline__ float fast_tanh(float x) {
  return 1.f - 2.f / (__expf(2.f * x) + 1.f);
}

// proj[N][128] = x[N][128] @ W[128][128], plus fused edge-histogram tail.
// 1 block/CU (133KB LDS) -> 1 wave/SIMD, so the k-loop is software-pipelined:
// k+1 fragments prefetched into registers before k's 64 FMAs issue.
__global__ __launch_bounds__(256, 1) void gemm_xW(const float* __restrict__ x,
                                                  const float* __restrict__ W,
                                                  float* __restrict__ proj, int N,
                                                  const int* __restrict__ ecol,
                                                  int* __restrict__ hist, int E) {
  __shared__ float xs[128][132];
  __shared__ float ws[128][128];
  const int tid = threadIdx.x;
  const int row0 = blockIdx.x * 128;

  {
    const float4* Wv = (const float4*)W;
    float4* wsv = (float4*)ws;
#pragma unroll
    for (int i = 0; i < 16; ++i) wsv[i * 256 + tid] = Wv[i * 256 + tid];
  }
  {
    const int r = tid >> 1;
    const int k0 = (tid & 1) * 64;
    const int grow = row0 + r;
    const bool valid = grow < N;
    const float4* src = (const float4*)(x + (size_t)grow * IN_CH + k0);
#pragma unroll
    for (int i = 0; i < 16; ++i) {
      float4 v = valid ? src[i] : make_float4(0.f, 0.f, 0.f, 0.f);
      const int k = k0 + i * 4;
      xs[k][r] = v.x; xs[k + 1][r] = v.y; xs[k + 2][r] = v.z; xs[k + 3][r] = v.w;
    }
  }
  __syncthreads();

  const int cg = tid & 15;
  const int rg = tid >> 4;
  const int rbase = rg * 8, cbase = cg * 8;
  float acc[8][8];
#pragma unroll
  for (int r = 0; r < 8; ++r)
#pragma unroll
    for (int c = 0; c < 8; ++c) acc[r][c] = 0.f;

  // 2-stage register pipeline over k
  float4 ca0 = *(const float4*)&xs[0][rbase];
  float4 ca1 = *(const float4*)&xs[0][rbase + 4];
  float4 cb0 = *(const float4*)&ws[0][cbase];
  float4 cb1 = *(const float4*)&ws[0][cbase + 4];
#pragma unroll 4
  for (int k = 0; k < 128; ++k) {
    const int kn = (k + 1) & 127;  // wraps to 0 on last iter (harmless reload)
    float4 na0 = *(const float4*)&xs[kn][rbase];
    float4 na1 = *(const float4*)&xs[kn][rbase + 4];
    float4 nb0 = *(const float4*)&ws[kn][cbase];
    float4 nb1 = *(const float4*)&ws[kn][cbase + 4];
    float xv[8] = {ca0.x, ca0.y, ca0.z, ca0.w, ca1.x, ca1.y, ca1.z, ca1.w};
    float wv[8] = {cb0.x, cb0.y, cb0.z, cb0.w, cb1.x, cb1.y, cb1.z, cb1.w};
#pragma unroll
    for (int r = 0; r < 8; ++r)
#pragma unroll
      for (int c = 0; c < 8; ++c) acc[r][c] += xv[r] * wv[c];
    ca0 = na0; ca1 = na1; cb0 = nb0; cb1 = nb1;
  }

#pragma unroll
  for (int r = 0; r < 8; ++r) {
    const int grow = row0 + rbase + r;
    if (grow < N) {
      float4* dst = (float4*)(proj + (size_t)grow * HC + cbase);
      dst[0] = make_float4(acc[r][0], acc[r][1], acc[r][2], acc[r][3]);
      dst[1] = make_float4(acc[r][4], acc[r][5], acc[r][6], acc[r][7]);
    }
  }

  // fused edge-histogram tail (independent of GEMM output)
  if (hist) {
    const int ehb = (E + gridDim.x - 1) / gridDim.x;
    const int estart = blockIdx.x * ehb;
    const int eend = min(estart + ehb, E);
    for (int e = estart + tid; e < eend; e += 256) atomicAdd(&hist[ecol[e]], 1);
  }
}

// --- hierarchical exclusive scan over nb counters ---
__device__ __forceinline__ int block_scan_excl(int tsum, int* ls, int tid, int* total) {
  ls[tid] = tsum;
  __syncthreads();
  for (int off = 1; off < 256; off <<= 1) {
    int v = (tid >= off) ? ls[tid - off] : 0;
    __syncthreads();
    ls[tid] += v;
    __syncthreads();
  }
  *total = ls[255];
  return ls[tid] - tsum;
}

__global__ __launch_bounds__(256) void k_scan_a(const int* __restrict__ hist,
                                                int* __restrict__ sums, int nb) {
  __shared__ int ls[256];
  const int tid = threadIdx.x;
  const int base = blockIdx.x * CHUNK + tid * 8;
  int t = 0;
#pragma unroll
  for (int j = 0; j < 8; ++j) { const int i = base + j; if (i < nb) t += hist[i]; }
  int total;
  block_scan_excl(t, ls, tid, &total);
  if (tid == 0) sums[blockIdx.x] = total;
}

__global__ __launch_bounds__(256) void k_scan_b(int* __restrict__ sums, int nc,
                                                int* __restrict__ starts,
                                                int* __restrict__ cursor, int nb) {
  __shared__ int ls[256];
  const int tid = threadIdx.x;
  const int t = (tid < nc) ? sums[tid] : 0;
  int total;
  const int excl = block_scan_excl(t, ls, tid, &total);
  if (tid < nc) sums[tid] = excl;
  if (tid == 0) { starts[nb] = total; cursor[nb] = total; }
}

__global__ __launch_bounds__(256) void k_scan_c(const int* __restrict__ hist,
                                                const int* __restrict__ sums,
                                                int* __restrict__ starts,
                                                int* __restrict__ cursor, int nb) {
  __shared__ int ls[256];
  const int tid = threadIdx.x;
  const int base = blockIdx.x * CHUNK + tid * 8;
  int t = 0;
#pragma unroll
  for (int j = 0; j < 8; ++j) { const int i = base + j; if (i < nb) t += hist[i]; }
  int total;
  const int excl = block_scan_excl(t, ls, tid, &total);
  int run = sums[blockIdx.x] + excl;
#pragma unroll
  for (int j = 0; j < 8; ++j) {
    const int i = base + j;
    if (i < nb) { starts[i] = run; cursor[i] = run; run += hist[i]; }
  }
}

// CSR permutation: rc[p] = src row * HC (pre-scaled float offset), grouped by dst.
__global__ __launch_bounds__(256) void scatter_rc(const int* __restrict__ erow,
                                                  const int* __restrict__ ecol,
                                                  int* __restrict__ cursor,
                                                  int* __restrict__ rc, int E) {
  const int i = blockIdx.x * 256 + threadIdx.x;
  if (i < E) {
    const int p = atomicAdd(&cursor[ecol[i]], 1);
    rc[p] = erow[i] * HC;
  }
}

// Wave per dst node, HALF-WAVE per edge, 8-edge main unroll: lane l (0..31)
// owns float4 of channels 4l..4l+3 (head = l>>3). rc holds pre-scaled row*HC so
// each gather address is a single add. Stabilizer = analytic bound
// M0_h = sum|att[h]| (cancels in the ratio); true per-head max tracked so
// fix_clamp reproduces max(norm,1e-12) exactly.
__global__ __launch_bounds__(256) void fused_apply(const float* __restrict__ proj,
                                                   const int* __restrict__ rc,
                                                   const int* __restrict__ starts,
                                                   const float* __restrict__ att,
                                                   float* __restrict__ out,
                                                   float* __restrict__ den,
                                                   unsigned* __restrict__ headmax_u, int N) {
  __shared__ unsigned blkmax[HEADS];
  const int tid = threadIdx.x;
  if (tid < HEADS) blkmax[tid] = 0u;
  __syncthreads();
  const int lane = tid & 63;
  const int half = lane >> 5;
  const int l = lane & 31;
  const int c0 = l * 4;
  const int head = l >> 3;
  const int n = blockIdx.x * 4 + (tid >> 6);
  float lm = -3.0e38f;

  if (n < N) {
    const float4 a4 = ((const float4*)att)[l];
    float M0 = fabsf(a4.x) + fabsf(a4.y) + fabsf(a4.z) + fabsf(a4.w);
    M0 += __shfl_xor(M0, 4, 64);
    M0 += __shfl_xor(M0, 2, 64);
    M0 += __shfl_xor(M0, 1, 64);
    const float4 d4 = *(const float4*)(proj + (size_t)n * HC + c0);
    const int beg = __builtin_amdgcn_readfirstlane(starts[n]);
    const int end = __builtin_amdgcn_readfirstlane(starts[n + 1]);

    float ax = 0.f, ay = 0.f, az = 0.f, aw = 0.f, dsum = 0.f;
    int i = beg;
    // main: 8 edges/iteration (4 per half-wave) -> 4 gathers in flight/lane
    for (; i + 8 <= end; i += 8) {
      const int r0 = rc[i + half];
      const int r1 = rc[i + 2 + half];
      const int r2 = rc[i + 4 + half];
      const int r3 = rc[i + 6 + half];
      const float4 s0 = *(const float4*)(proj + r0 + c0);
      const float4 s1 = *(const float4*)(proj + r1 + c0);
      const float4 s2 = *(const float4*)(proj + r2 + c0);
      const float4 s3 = *(const float4*)(proj + r3 + c0);
      float p0 = fast_tanh(s0.x + d4.x) * a4.x + fast_tanh(s0.y + d4.y) * a4.y
               + fast_tanh(s0.z + d4.z) * a4.z + fast_tanh(s0.w + d4.w) * a4.w;
      float p1 = fast_tanh(s1.x + d4.x) * a4.x + fast_tanh(s1.y + d4.y) * a4.y
               + fast_tanh(s1.z + d4.z) * a4.z + fast_tanh(s1.w + d4.w) * a4.w;
      float p2 = fast_tanh(s2.x + d4.x) * a4.x + fast_tanh(s2.y + d4.y) * a4.y
               + fast_tanh(s2.z + d4.z) * a4.z + fast_tanh(s2.w + d4.w) * a4.w;
      float p3 = fast_tanh(s3.x + d4.x) * a4.x + fast_tanh(s3.y + d4.y) * a4.y
               + fast_tanh(s3.z + d4.z) * a4.z + fast_tanh(s3.w + d4.w) * a4.w;
      p0 += __shfl_xor(p0, 4, 64);  p1 += __shfl_xor(p1, 4, 64);
      p2 += __shfl_xor(p2, 4, 64);  p3 += __shfl_xor(p3, 4, 64);
      p0 += __shfl_xor(p0, 2, 64);  p1 += __shfl_xor(p1, 2, 64);
      p2 += __shfl_xor(p2, 2, 64);  p3 += __shfl_xor(p3, 2, 64);
      p0 += __shfl_xor(p0, 1, 64);  p1 += __shfl_xor(p1, 1, 64);
      p2 += __shfl_xor(p2, 1, 64);  p3 += __shfl_xor(p3, 1, 64);
      lm = fmaxf(lm, fmaxf(fmaxf(p0, p1), fmaxf(p2, p3)));
      const float e0 = __expf(p0 - M0);
      const float e1 = __expf(p1 - M0);
      const float e2 = __expf(p2 - M0);
      const float e3 = __expf(p3 - M0);
      ax += s0.x * e0 + s1.x * e1 + s2.x * e2 + s3.x * e3;
      ay += s0.y * e0 + s1.y * e1 + s2.y * e2 + s3.y * e3;
      az += s0.z * e0 + s1.z * e1 + s2.z * e2 + s3.z * e3;
      aw += s0.w * e0 + s1.w * e1 + s2.w * e2 + s3.w * e3;
      dsum += (e0 + e1) + (e2 + e3);
    }
    // middle: one 4-edge step
    if (i + 4 <= end) {
      const int r0 = rc[i + half];
      const int r1 = rc[i + 2 + half];
      const float4 s0 = *(const float4*)(proj + r0 + c0);
      const float4 s1 = *(const float4*)(proj + r1 + c0);
      float p0 = fast_tanh(s0.x + d4.x) * a4.x + fast_tanh(s0.y + d4.y) * a4.y
               + fast_tanh(s0.z + d4.z) * a4.z + fast_tanh(s0.w + d4.w) * a4.w;
      float p1 = fast_tanh(s1.x + d4.x) * a4.x + fast_tanh(s1.y + d4.y) * a4.y
               + fast_tanh(s1.z + d4.z) * a4.z + fast_tanh(s1.w + d4.w) * a4.w;
      p0 += __shfl_xor(p0, 4, 64);  p1 += __shfl_xor(p1, 4, 64);
      p0 += __shfl_xor(p0, 2, 64);  p1 += __shfl_xor(p1, 2, 64);
      p0 += __shfl_xor(p0, 1, 64);  p1 += __shfl_xor(p1, 1, 64);
      lm = fmaxf(lm, fmaxf(p0, p1));
      const float e0 = __expf(p0 - M0);
      const float e1 = __expf(p1 - M0);
      ax += s0.x * e0 + s1.x * e1;
      ay += s0.y * e0 + s1.y * e1;
      az += s0.z * e0 + s1.z * e1;
      aw += s0.w * e0 + s1.w * e1;
      dsum += e0 + e1;
      i += 4;
    }
    // tail: 2 edges/iteration, masked
    for (; i < end; i += 2) {
      const int idx = i + half;
      const bool valid = idx < end;
      const int row = rc[valid ? idx : i];
      const float4 s4 = *(const float4*)(proj + row + c0);
      float p = fast_tanh(s4.x + d4.x) * a4.x
              + fast_tanh(s4.y + d4.y) * a4.y
              + fast_tanh(s4.z + d4.z) * a4.z
              + fast_tanh(s4.w + d4.w) * a4.w;
      p += __shfl_xor(p, 4, 64);
      p += __shfl_xor(p, 2, 64);
      p += __shfl_xor(p, 1, 64);
      if (!valid) p = -3.0e38f;
      lm = fmaxf(lm, p);
      const float e = __expf(p - M0);
      ax += s4.x * e; ay += s4.y * e; az += s4.z * e; aw += s4.w * e;
      dsum += e;
    }
    // merge halves
    dsum += __shfl_xor(dsum, 32, 64);
    ax += __shfl_xor(ax, 32, 64);
    ay += __shfl_xor(ay, 32, 64);
    az += __shfl_xor(az, 32, 64);
    aw += __shfl_xor(aw, 32, 64);
    lm = fmaxf(lm, __shfl_xor(lm, 32, 64));
    if (half == 0) {
      const float inv = 1.f / fmaxf(dsum, 1e-38f);
      *(float4*)(out + (size_t)n * HC + c0) =
          make_float4(ax * inv, ay * inv, az * inv, aw * inv);
      if ((l & 7) == 0) den[n * HEADS + head] = dsum;
      if ((l & 7) == 0) atomicMax(&blkmax[head], flip_f32(lm));
    }
  }
  __syncthreads();
  if (tid < HEADS) {
    const unsigned v = blkmax[tid];
    if (v > headmax_u[tid]) atomicMax(&headmax_u[tid], v);
  }
}

// Reference normalizer = den * exp(M0_h - Mt_h). If below 1e-12 the reference
// clamps: out_ref = out_ours * (ref_den / 1e-12). Apply that correction.
__global__ __launch_bounds__(256) void fix_clamp(float* __restrict__ out,
                                                 const float* __restrict__ den,
                                                 const unsigned* __restrict__ headmax_u,
                                                 const float* __restrict__ att, int N) {
  const int t = blockIdx.x * 256 + threadIdx.x;
  if (t >= N * HEADS) return;
  const int n = t >> 2;
  const int h = t & 3;
  float M0 = 0.f;
#pragma unroll
  for (int c = 0; c < OUT_CH; ++c) M0 += fabsf(att[h * OUT_CH + c]);
  const float Mt = unflip_f32(headmax_u[h]);
  const float f = den[t] * __expf(M0 - Mt);
  if (f < 1e-12f) {
    const float s = f * 1e12f;
    float4* p = (float4*)(out + (size_t)n * HC + h * OUT_CH);
#pragma unroll
    for (int j = 0; j < 8; ++j) {
      float4 v = p[j];
      v.x *= s; v.y *= s; v.z *= s; v.w *= s;
      p[j] = v;
    }
  }
}

// blockmax -> corr (fallback path only)
__global__ __launch_bounds__(256) void reduce_corr(const unsigned* __restrict__ blockmax,
                                                   const float* __restrict__ att,
                                                   float* __restrict__ corr, int nblk) {
  __shared__ unsigned sm[HEADS];
  const int tid = threadIdx.x;
  if (tid < HEADS) sm[tid] = 0u;
  __syncthreads();
  const int h = tid & 3;
  unsigned k = 0u;
  for (int i = tid >> 2; i < nblk; i += 64) k = max(k, blockmax[i * HEADS + h]);
  atomicMax(&sm[h], k);
  __syncthreads();
  if (tid < HEADS) {
    const float Mt = unflip_f32(sm[tid]);
    float M0 = 0.f;
#pragma unroll
    for (int c = 0; c < OUT_CH; ++c) M0 += fabsf(att[tid * OUT_CH + c]);
    corr[tid] = __expf(M0 - Mt);
    corr[4 + tid] = Mt;
  }
}

// --- fallback path (ws too small): score-max pass + edge-parallel atomics ---
__global__ __launch_bounds__(256) void score_max(const float* __restrict__ proj,
                                                 const int* __restrict__ erow,
                                                 const int* __restrict__ ecol,
                                                 const float* __restrict__ att,
                                                 unsigned* __restrict__ blockmax, int E) {
  __shared__ unsigned blkmax[HEADS];
  const int tid = threadIdx.x;
  if (tid < HEADS) blkmax[tid] = 0u;
  __syncthreads();
  const int lane = tid & 63;
  const int wid = tid >> 6;
  const float a0 = att[lane];
  const float a1 = att[lane + 64];
  float lmA = -3.0e38f, lmB = -3.0e38f;
  const int stride = SCORE_BLOCKS * 16;

  for (int base = (blockIdx.x * 4 + wid) * 4; base < E; base += stride) {
    const int bu = __builtin_amdgcn_readfirstlane(base);
    const int lim = min(bu + 4, E);
    for (int e = bu; e < lim; ++e) {
      const int r0 = erow[e], c0 = ecol[e];
      const float* ps = proj + (size_t)r0 * HC;
      const float* pd = proj + (size_t)c0 * HC;
      float pA = fast_tanh(ps[lane] + pd[lane]) * a0;
      float pB = fast_tanh(ps[lane + 64] + pd[lane + 64]) * a1;
#pragma unroll
      for (int m = 16; m >= 1; m >>= 1) {
        pA += __shfl_xor(pA, m, 64);
        pB += __shfl_xor(pB, m, 64);
      }
      lmA = fmaxf(lmA, pA);
      lmB = fmaxf(lmB, pB);
    }
  }
  if ((lane & 31) == 0) {
    const int hh = lane >> 5;
    atomicMax(&blkmax[hh], flip_f32(lmA));
    atomicMax(&blkmax[hh + 2], flip_f32(lmB));
  }
  __syncthreads();
  if (tid < HEADS) blockmax[blockIdx.x * HEADS + tid] = blkmax[tid];
}

__global__ __launch_bounds__(256) void edge_apply_fb(const float* __restrict__ proj,
                                                     const int* __restrict__ erow,
                                                     const int* __restrict__ ecol,
                                                     const float* __restrict__ att,
                                                     const float* __restrict__ headmax,
                                                     float* __restrict__ out,
                                                     float* __restrict__ norm, int E) {
  const int tid = threadIdx.x;
  const int e = blockIdx.x * 2 + (tid >> 7);
  if (e >= E) return;
  const int ch = tid & 127;
  const int h = ch >> 5;
  const float M = headmax[h];
  const int row = erow[e];
  const int col = ecol[e];
  const float sv = proj[(size_t)row * HC + ch];
  const float dv = proj[(size_t)col * HC + ch];
  float p = fast_tanh(sv + dv) * att[ch];
#pragma unroll
  for (int m = 16; m >= 1; m >>= 1) p += __shfl_xor(p, m, 64);
  const float w = __expf(p - M);
  unsafeAtomicAdd(&out[(size_t)col * HC + ch], sv * w);
  if ((ch & 31) == 0) unsafeAtomicAdd(&norm[(size_t)col * HEADS + h], w);
}

__global__ __launch_bounds__(256) void finalize_fb(float* __restrict__ out,
                                                   const float* __restrict__ norm, int N) {
  const int idx = blockIdx.x * blockDim.x + threadIdx.x;
  const int total = N * (HC / 4);
  if (idx >= total) return;
  const int base = idx * 4;
  const int node = base >> 7;
  const int h = (base >> 5) & 3;
  const float inv = 1.f / fmaxf(norm[node * HEADS + h], 1e-12f);
  float4 v = ((float4*)out)[idx];
  v.x *= inv; v.y *= inv; v.z *= inv; v.w *= inv;
  ((float4*)out)[idx] = v;
}

extern "C" void kernel_launch(void* const* d_in, const int* in_sizes, int n_in,
                              void* d_out, int out_size, void* d_ws, size_t ws_size,
                              hipStream_t stream) {
  const float* x    = (const float*)d_in[0];
  const int*   eidx = (const int*)d_in[1];  // [2][E]: row(src) then col(dst)
  const float* W    = (const float*)d_in[2];
  const float* att  = (const float*)d_in[3];
  float* out = (float*)d_out;

  const int N = in_sizes[0] / IN_CH;
  const int E = in_sizes[1] / 2;
  const int nb = N;
  const int nc = (nb + CHUNK - 1) / CHUNK;  // scan chunks (<=256 supported)

  // ws layout (16B-aligned pieces)
  char* p = (char*)d_ws;
  float* proj = (float*)p;  p += (size_t)N * HC * 4;
  int* rc = (int*)p;        p += (((size_t)E * 4 + 15) & ~15ull);
  float* den = (float*)p;   p += (((size_t)N * HEADS * 4 + 15) & ~15ull);
  int* hist = (int*)p;      p += (((size_t)(nb + 4) * 4 + 15) & ~15ull);  // +4: headmax_u
  int* starts = (int*)p;    p += (((size_t)(nb + 1) * 4 + 15) & ~15ull);
  int* cursor = (int*)p;    p += (((size_t)(nb + 1) * 4 + 15) & ~15ull);
  int* sums = (int*)p;      p += 1024;
  unsigned* headmax_u = (unsigned*)(hist + nb);
  const size_t need_full = (size_t)(p - (char*)d_ws);
  const bool full = (ws_size >= need_full) && (nc <= 256);

  if (full) {
    hipMemsetAsync(hist, 0, (size_t)(nb + 4) * sizeof(int), stream);  // hist + headmax_u
    gemm_xW<<<(N + 127) / 128, 256, 0, stream>>>(x, W, proj, N, eidx + E, hist, E);
    k_scan_a<<<nc, 256, 0, stream>>>(hist, sums, nb);
    k_scan_b<<<1, 256, 0, stream>>>(sums, nc, starts, cursor, nb);
    k_scan_c<<<nc, 256, 0, stream>>>(hist, sums, starts, cursor, nb);
    scatter_rc<<<(E + 255) / 256, 256, 0, stream>>>(eidx, eidx + E, cursor, rc, E);
    fused_apply<<<(N + 3) / 4, 256, 0, stream>>>(proj, rc, starts, att, out, den,
                                                 headmax_u, N);
    fix_clamp<<<(N * HEADS + 255) / 256, 256, 0, stream>>>(out, den, headmax_u, att, N);
  } else {
    // minimal-ws fallback: blockmax/corr/norm packed right after proj
    gemm_xW<<<(N + 127) / 128, 256, 0, stream>>>(x, W, proj, N, nullptr, nullptr, 0);
    unsigned* bm = (unsigned*)(proj + (size_t)N * HC);
    float* cr = (float*)(bm + SCORE_BLOCKS * HEADS);
    float* norm = cr + 8;
    hipMemsetAsync(out, 0, (size_t)out_size * sizeof(float), stream);
    hipMemsetAsync(norm, 0, (size_t)N * HEADS * sizeof(float), stream);
    score_max<<<SCORE_BLOCKS, 256, 0, stream>>>(proj, eidx, eidx + E, att, bm, E);
    reduce_corr<<<1, 256, 0, stream>>>(bm, att, cr, SCORE_BLOCKS);
    edge_apply_fb<<<(E + 1) / 2, 256, 0, stream>>>(proj, eidx, eidx + E, att, cr + 4, out, norm, E);
    finalize_fb<<<(N * (HC / 4) + 255) / 256, 256, 0, stream>>>(out, norm, N);
  }
}

// Round 6
// 481.396 us; speedup vs baseline: 1.4100x; 1.0693x over previous
//
#include <hip/hip_runtime.h>

#define IN_CH 128
#define HEADS 4
#define OUT_CH 32
#define HC 128           // HEADS*OUT_CH
#define SCORE_BLOCKS 4096
#define CHUNK 2048       // scan chunk (256 thr x 8)

__device__ __forceinline__ unsigned flip_f32(float x) {
  unsigned u = __float_as_uint(x);
  return (u & 0x80000000u) ? ~u : (u | 0x80000000u);
}
__device__ __forceinline__ float unflip_f32(unsigned k) {
  unsigned u = (k & 0x80000000u) ? (k ^ 0x80000000u) : ~k;
  return __uint_as_float(u);
}
// tanh(x) = 1 - 2/(e^{2x}+1); e^{2x} = 2^{x * 2*log2(e)} -> single v_exp_f32
__device__ __forceinline__ float fast_tanh(float x) {
#if __has_builtin(__builtin_amdgcn_exp2f)
  const float t = __builtin_amdgcn_exp2f(x * 2.8853900817779268f);
#else
  const float t = __expf(2.f * x);
#endif
  return 1.f - 2.f / (t + 1.f);
}

// proj[N][128] = x[N][128] @ W[128][128], 64x64 tiles -> 69.6KB LDS
// -> 2 blocks/CU (8 waves/CU) for latency hiding; plus fused edge-histogram.
__global__ __launch_bounds__(256) void gemm_xW(const float* __restrict__ x,
                                               const float* __restrict__ W,
                                               float* __restrict__ proj, int N,
                                               const int* __restrict__ ecol,
                                               int* __restrict__ hist, int E) {
  __shared__ float xs[128][68];  // [k][r]
  __shared__ float ws[128][68];  // [k][c]
  const int tid = threadIdx.x;
  const int rowblk = blockIdx.x >> 1;
  const int colblk = blockIdx.x & 1;
  const int row0 = rowblk * 64;
  const int col0 = colblk * 64;

  // W tile: thread t loads row k = t>>1, 32 cols starting at (t&1)*32
  {
    const int k = tid >> 1;
    const int c0 = (tid & 1) * 32;
    const float4* src = (const float4*)(W + (size_t)k * HC + col0 + c0);
#pragma unroll
    for (int i = 0; i < 8; ++i) *(float4*)&ws[k][c0 + i * 4] = src[i];
  }
  // x tile (transposed): thread t loads row r = t>>2, 32 ks starting at (t&3)*32
  {
    const int r = tid >> 2;
    const int k0 = (tid & 3) * 32;
    const int grow = row0 + r;
    const bool valid = grow < N;
    const float4* src = (const float4*)(x + (size_t)grow * IN_CH + k0);
#pragma unroll
    for (int i = 0; i < 8; ++i) {
      float4 v = valid ? src[i] : make_float4(0.f, 0.f, 0.f, 0.f);
      const int k = k0 + i * 4;
      xs[k][r] = v.x; xs[k + 1][r] = v.y; xs[k + 2][r] = v.z; xs[k + 3][r] = v.w;
    }
  }
  __syncthreads();

  const int cg = tid & 15;
  const int rg = tid >> 4;
  float acc[4][4];
#pragma unroll
  for (int r = 0; r < 4; ++r)
#pragma unroll
    for (int c = 0; c < 4; ++c) acc[r][c] = 0.f;

#pragma unroll 8
  for (int k = 0; k < 128; ++k) {
    const float4 a = *(const float4*)&xs[k][rg * 4];
    const float4 b = *(const float4*)&ws[k][cg * 4];
    const float xv[4] = {a.x, a.y, a.z, a.w};
    const float wv[4] = {b.x, b.y, b.z, b.w};
#pragma unroll
    for (int r = 0; r < 4; ++r)
#pragma unroll
      for (int c = 0; c < 4; ++c) acc[r][c] += xv[r] * wv[c];
  }

#pragma unroll
  for (int r = 0; r < 4; ++r) {
    const int grow = row0 + rg * 4 + r;
    if (grow < N) {
      *(float4*)(proj + (size_t)grow * HC + col0 + cg * 4) =
          make_float4(acc[r][0], acc[r][1], acc[r][2], acc[r][3]);
    }
  }

  // fused edge-histogram tail (independent of GEMM output)
  if (hist) {
    const int ehb = (E + gridDim.x - 1) / gridDim.x;
    const int estart = blockIdx.x * ehb;
    const int eend = min(estart + ehb, E);
    for (int e = estart + tid; e < eend; e += 256) atomicAdd(&hist[ecol[e]], 1);
  }
}

// --- hierarchical exclusive scan over nb counters ---
__device__ __forceinline__ int block_scan_excl(int tsum, int* ls, int tid, int* total) {
  ls[tid] = tsum;
  __syncthreads();
  for (int off = 1; off < 256; off <<= 1) {
    int v = (tid >= off) ? ls[tid - off] : 0;
    __syncthreads();
    ls[tid] += v;
    __syncthreads();
  }
  *total = ls[255];
  return ls[tid] - tsum;
}

__global__ __launch_bounds__(256) void k_scan_a(const int* __restrict__ hist,
                                                int* __restrict__ sums, int nb) {
  __shared__ int ls[256];
  const int tid = threadIdx.x;
  const int base = blockIdx.x * CHUNK + tid * 8;
  int t = 0;
#pragma unroll
  for (int j = 0; j < 8; ++j) { const int i = base + j; if (i < nb) t += hist[i]; }
  int total;
  block_scan_excl(t, ls, tid, &total);
  if (tid == 0) sums[blockIdx.x] = total;
}

// k_scan_c with the chunk-level prefix folded in: each block sums the raw
// chunk totals below it (<=48 uniform L2 reads) instead of a separate pass.
__global__ __launch_bounds__(256) void k_scan_c(const int* __restrict__ hist,
                                                const int* __restrict__ sums,
                                                int* __restrict__ starts,
                                                int* __restrict__ cursor,
                                                int nb, int nc) {
  __shared__ int ls[256];
  const int tid = threadIdx.x;
  const int base = blockIdx.x * CHUNK + tid * 8;
  int t = 0;
#pragma unroll
  for (int j = 0; j < 8; ++j) { const int i = base + j; if (i < nb) t += hist[i]; }
  int total;
  const int excl = block_scan_excl(t, ls, tid, &total);
  int cbase = 0;
  for (int j = 0; j < blockIdx.x; ++j) cbase += sums[j];
  int run = cbase + excl;
#pragma unroll
  for (int j = 0; j < 8; ++j) {
    const int i = base + j;
    if (i < nb) { starts[i] = run; cursor[i] = run; run += hist[i]; }
  }
  if (blockIdx.x == nc - 1 && tid == 0) {
    const int grand = cbase + total;
    starts[nb] = grand;
    cursor[nb] = grand;
  }
}

// CSR permutation: rc[p] = src row * HC (pre-scaled float offset), grouped by dst.
__global__ __launch_bounds__(256) void scatter_rc(const int* __restrict__ erow,
                                                  const int* __restrict__ ecol,
                                                  int* __restrict__ cursor,
                                                  int* __restrict__ rc, int E) {
  const int i = blockIdx.x * 256 + threadIdx.x;
  if (i < E) {
    const int p = atomicAdd(&cursor[ecol[i]], 1);
    rc[p] = erow[i] * HC;
  }
}

// Wave per dst node, HALF-WAVE per edge, 8-edge main unroll: lane l (0..31)
// owns float4 of channels 4l..4l+3 (head = l>>3). rc holds pre-scaled row*HC so
// each gather address is a single add. Stabilizer = analytic bound
// M0_h = sum|att[h]| (cancels in the ratio); true per-head max tracked so
// fix_clamp reproduces max(norm,1e-12) exactly.
__global__ __launch_bounds__(256) void fused_apply(const float* __restrict__ proj,
                                                   const int* __restrict__ rc,
                                                   const int* __restrict__ starts,
                                                   const float* __restrict__ att,
                                                   float* __restrict__ out,
                                                   float* __restrict__ den,
                                                   unsigned* __restrict__ headmax_u, int N) {
  __shared__ unsigned blkmax[HEADS];
  const int tid = threadIdx.x;
  if (tid < HEADS) blkmax[tid] = 0u;
  __syncthreads();
  const int lane = tid & 63;
  const int half = lane >> 5;
  const int l = lane & 31;
  const int c0 = l * 4;
  const int head = l >> 3;
  const int n = blockIdx.x * 4 + (tid >> 6);
  float lm = -3.0e38f;

  if (n < N) {
    const float4 a4 = ((const float4*)att)[l];
    float M0 = fabsf(a4.x) + fabsf(a4.y) + fabsf(a4.z) + fabsf(a4.w);
    M0 += __shfl_xor(M0, 4, 64);
    M0 += __shfl_xor(M0, 2, 64);
    M0 += __shfl_xor(M0, 1, 64);
    const float4 d4 = *(const float4*)(proj + (size_t)n * HC + c0);
    const int beg = __builtin_amdgcn_readfirstlane(starts[n]);
    const int end = __builtin_amdgcn_readfirstlane(starts[n + 1]);

    float ax = 0.f, ay = 0.f, az = 0.f, aw = 0.f, dsum = 0.f;
    int i = beg;
    // main: 8 edges/iteration (4 per half-wave) -> 4 gathers in flight/lane
    for (; i + 8 <= end; i += 8) {
      const int r0 = rc[i + half];
      const int r1 = rc[i + 2 + half];
      const int r2 = rc[i + 4 + half];
      const int r3 = rc[i + 6 + half];
      const float4 s0 = *(const float4*)(proj + r0 + c0);
      const float4 s1 = *(const float4*)(proj + r1 + c0);
      const float4 s2 = *(const float4*)(proj + r2 + c0);
      const float4 s3 = *(const float4*)(proj + r3 + c0);
      float p0 = fast_tanh(s0.x + d4.x) * a4.x + fast_tanh(s0.y + d4.y) * a4.y
               + fast_tanh(s0.z + d4.z) * a4.z + fast_tanh(s0.w + d4.w) * a4.w;
      float p1 = fast_tanh(s1.x + d4.x) * a4.x + fast_tanh(s1.y + d4.y) * a4.y
               + fast_tanh(s1.z + d4.z) * a4.z + fast_tanh(s1.w + d4.w) * a4.w;
      float p2 = fast_tanh(s2.x + d4.x) * a4.x + fast_tanh(s2.y + d4.y) * a4.y
               + fast_tanh(s2.z + d4.z) * a4.z + fast_tanh(s2.w + d4.w) * a4.w;
      float p3 = fast_tanh(s3.x + d4.x) * a4.x + fast_tanh(s3.y + d4.y) * a4.y
               + fast_tanh(s3.z + d4.z) * a4.z + fast_tanh(s3.w + d4.w) * a4.w;
      p0 += __shfl_xor(p0, 4, 64);  p1 += __shfl_xor(p1, 4, 64);
      p2 += __shfl_xor(p2, 4, 64);  p3 += __shfl_xor(p3, 4, 64);
      p0 += __shfl_xor(p0, 2, 64);  p1 += __shfl_xor(p1, 2, 64);
      p2 += __shfl_xor(p2, 2, 64);  p3 += __shfl_xor(p3, 2, 64);
      p0 += __shfl_xor(p0, 1, 64);  p1 += __shfl_xor(p1, 1, 64);
      p2 += __shfl_xor(p2, 1, 64);  p3 += __shfl_xor(p3, 1, 64);
      lm = fmaxf(lm, fmaxf(fmaxf(p0, p1), fmaxf(p2, p3)));
      const float e0 = __expf(p0 - M0);
      const float e1 = __expf(p1 - M0);
      const float e2 = __expf(p2 - M0);
      const float e3 = __expf(p3 - M0);
      ax += s0.x * e0 + s1.x * e1 + s2.x * e2 + s3.x * e3;
      ay += s0.y * e0 + s1.y * e1 + s2.y * e2 + s3.y * e3;
      az += s0.z * e0 + s1.z * e1 + s2.z * e2 + s3.z * e3;
      aw += s0.w * e0 + s1.w * e1 + s2.w * e2 + s3.w * e3;
      dsum += (e0 + e1) + (e2 + e3);
    }
    // middle: one 4-edge step
    if (i + 4 <= end) {
      const int r0 = rc[i + half];
      const int r1 = rc[i + 2 + half];
      const float4 s0 = *(const float4*)(proj + r0 + c0);
      const float4 s1 = *(const float4*)(proj + r1 + c0);
      float p0 = fast_tanh(s0.x + d4.x) * a4.x + fast_tanh(s0.y + d4.y) * a4.y
               + fast_tanh(s0.z + d4.z) * a4.z + fast_tanh(s0.w + d4.w) * a4.w;
      float p1 = fast_tanh(s1.x + d4.x) * a4.x + fast_tanh(s1.y + d4.y) * a4.y
               + fast_tanh(s1.z + d4.z) * a4.z + fast_tanh(s1.w + d4.w) * a4.w;
      p0 += __shfl_xor(p0, 4, 64);  p1 += __shfl_xor(p1, 4, 64);
      p0 += __shfl_xor(p0, 2, 64);  p1 += __shfl_xor(p1, 2, 64);
      p0 += __shfl_xor(p0, 1, 64);  p1 += __shfl_xor(p1, 1, 64);
      lm = fmaxf(lm, fmaxf(p0, p1));
      const float e0 = __expf(p0 - M0);
      const float e1 = __expf(p1 - M0);
      ax += s0.x * e0 + s1.x * e1;
      ay += s0.y * e0 + s1.y * e1;
      az += s0.z * e0 + s1.z * e1;
      aw += s0.w * e0 + s1.w * e1;
      dsum += e0 + e1;
      i += 4;
    }
    // tail: 2 edges/iteration, masked
    for (; i < end; i += 2) {
      const int idx = i + half;
      const bool valid = idx < end;
      const int row = rc[valid ? idx : i];
      const float4 s4 = *(const float4*)(proj + row + c0);
      float p = fast_tanh(s4.x + d4.x) * a4.x
              + fast_tanh(s4.y + d4.y) * a4.y
              + fast_tanh(s4.z + d4.z) * a4.z
              + fast_tanh(s4.w + d4.w) * a4.w;
      p += __shfl_xor(p, 4, 64);
      p += __shfl_xor(p, 2, 64);
      p += __shfl_xor(p, 1, 64);
      if (!valid) p = -3.0e38f;
      lm = fmaxf(lm, p);
      const float e = __expf(p - M0);
      ax += s4.x * e; ay += s4.y * e; az += s4.z * e; aw += s4.w * e;
      dsum += e;
    }
    // merge halves
    dsum += __shfl_xor(dsum, 32, 64);
    ax += __shfl_xor(ax, 32, 64);
    ay += __shfl_xor(ay, 32, 64);
    az += __shfl_xor(az, 32, 64);
    aw += __shfl_xor(aw, 32, 64);
    lm = fmaxf(lm, __shfl_xor(lm, 32, 64));
    if (half == 0) {
      const float inv = 1.f / fmaxf(dsum, 1e-38f);
      *(float4*)(out + (size_t)n * HC + c0) =
          make_float4(ax * inv, ay * inv, az * inv, aw * inv);
      if ((l & 7) == 0) den[n * HEADS + head] = dsum;
      if ((l & 7) == 0) atomicMax(&blkmax[head], flip_f32(lm));
    }
  }
  __syncthreads();
  if (tid < HEADS) {
    const unsigned v = blkmax[tid];
    if (v > headmax_u[tid]) atomicMax(&headmax_u[tid], v);
  }
}

// Reference normalizer = den * exp(M0_h - Mt_h). If below 1e-12 the reference
// clamps: out_ref = out_ours * (ref_den / 1e-12). Apply that correction.
__global__ __launch_bounds__(256) void fix_clamp(float* __restrict__ out,
                                                 const float* __restrict__ den,
                                                 const unsigned* __restrict__ headmax_u,
                                                 const float* __restrict__ att, int N) {
  const int t = blockIdx.x * 256 + threadIdx.x;
  if (t >= N * HEADS) return;
  const int n = t >> 2;
  const int h = t & 3;
  float M0 = 0.f;
#pragma unroll
  for (int c = 0; c < OUT_CH; ++c) M0 += fabsf(att[h * OUT_CH + c]);
  const float Mt = unflip_f32(headmax_u[h]);
  const float f = den[t] * __expf(M0 - Mt);
  if (f < 1e-12f) {
    const float s = f * 1e12f;
    float4* p = (float4*)(out + (size_t)n * HC + h * OUT_CH);
#pragma unroll
    for (int j = 0; j < 8; ++j) {
      float4 v = p[j];
      v.x *= s; v.y *= s; v.z *= s; v.w *= s;
      p[j] = v;
    }
  }
}

// blockmax -> corr (fallback path only)
__global__ __launch_bounds__(256) void reduce_corr(const unsigned* __restrict__ blockmax,
                                                   const float* __restrict__ att,
                                                   float* __restrict__ corr, int nblk) {
  __shared__ unsigned sm[HEADS];
  const int tid = threadIdx.x;
  if (tid < HEADS) sm[tid] = 0u;
  __syncthreads();
  const int h = tid & 3;
  unsigned k = 0u;
  for (int i = tid >> 2; i < nblk; i += 64) k = max(k, blockmax[i * HEADS + h]);
  atomicMax(&sm[h], k);
  __syncthreads();
  if (tid < HEADS) {
    const float Mt = unflip_f32(sm[tid]);
    float M0 = 0.f;
#pragma unroll
    for (int c = 0; c < OUT_CH; ++c) M0 += fabsf(att[tid * OUT_CH + c]);
    corr[tid] = __expf(M0 - Mt);
    corr[4 + tid] = Mt;
  }
}

// --- fallback path (ws too small): score-max pass + edge-parallel atomics ---
__global__ __launch_bounds__(256) void score_max(const float* __restrict__ proj,
                                                 const int* __restrict__ erow,
                                                 const int* __restrict__ ecol,
                                                 const float* __restrict__ att,
                                                 unsigned* __restrict__ blockmax, int E) {
  __shared__ unsigned blkmax[HEADS];
  const int tid = threadIdx.x;
  if (tid < HEADS) blkmax[tid] = 0u;
  __syncthreads();
  const int lane = tid & 63;
  const int wid = tid >> 6;
  const float a0 = att[lane];
  const float a1 = att[lane + 64];
  float lmA = -3.0e38f, lmB = -3.0e38f;
  const int stride = SCORE_BLOCKS * 16;

  for (int base = (blockIdx.x * 4 + wid) * 4; base < E; base += stride) {
    const int bu = __builtin_amdgcn_readfirstlane(base);
    const int lim = min(bu + 4, E);
    for (int e = bu; e < lim; ++e) {
      const int r0 = erow[e], c0 = ecol[e];
      const float* ps = proj + (size_t)r0 * HC;
      const float* pd = proj + (size_t)c0 * HC;
      float pA = fast_tanh(ps[lane] + pd[lane]) * a0;
      float pB = fast_tanh(ps[lane + 64] + pd[lane + 64]) * a1;
#pragma unroll
      for (int m = 16; m >= 1; m >>= 1) {
        pA += __shfl_xor(pA, m, 64);
        pB += __shfl_xor(pB, m, 64);
      }
      lmA = fmaxf(lmA, pA);
      lmB = fmaxf(lmB, pB);
    }
  }
  if ((lane & 31) == 0) {
    const int hh = lane >> 5;
    atomicMax(&blkmax[hh], flip_f32(lmA));
    atomicMax(&blkmax[hh + 2], flip_f32(lmB));
  }
  __syncthreads();
  if (tid < HEADS) blockmax[blockIdx.x * HEADS + tid] = blkmax[tid];
}

__global__ __launch_bounds__(256) void edge_apply_fb(const float* __restrict__ proj,
                                                     const int* __restrict__ erow,
                                                     const int* __restrict__ ecol,
                                                     const float* __restrict__ att,
                                                     const float* __restrict__ headmax,
                                                     float* __restrict__ out,
                                                     float* __restrict__ norm, int E) {
  const int tid = threadIdx.x;
  const int e = blockIdx.x * 2 + (tid >> 7);
  if (e >= E) return;
  const int ch = tid & 127;
  const int h = ch >> 5;
  const float M = headmax[h];
  const int row = erow[e];
  const int col = ecol[e];
  const float sv = proj[(size_t)row * HC + ch];
  const float dv = proj[(size_t)col * HC + ch];
  float p = fast_tanh(sv + dv) * att[ch];
#pragma unroll
  for (int m = 16; m >= 1; m >>= 1) p += __shfl_xor(p, m, 64);
  const float w = __expf(p - M);
  unsafeAtomicAdd(&out[(size_t)col * HC + ch], sv * w);
  if ((ch & 31) == 0) unsafeAtomicAdd(&norm[(size_t)col * HEADS + h], w);
}

__global__ __launch_bounds__(256) void finalize_fb(float* __restrict__ out,
                                                   const float* __restrict__ norm, int N) {
  const int idx = blockIdx.x * blockDim.x + threadIdx.x;
  const int total = N * (HC / 4);
  if (idx >= total) return;
  const int base = idx * 4;
  const int node = base >> 7;
  const int h = (base >> 5) & 3;
  const float inv = 1.f / fmaxf(norm[node * HEADS + h], 1e-12f);
  float4 v = ((float4*)out)[idx];
  v.x *= inv; v.y *= inv; v.z *= inv; v.w *= inv;
  ((float4*)out)[idx] = v;
}

extern "C" void kernel_launch(void* const* d_in, const int* in_sizes, int n_in,
                              void* d_out, int out_size, void* d_ws, size_t ws_size,
                              hipStream_t stream) {
  const float* x    = (const float*)d_in[0];
  const int*   eidx = (const int*)d_in[1];  // [2][E]: row(src) then col(dst)
  const float* W    = (const float*)d_in[2];
  const float* att  = (const float*)d_in[3];
  float* out = (float*)d_out;

  const int N = in_sizes[0] / IN_CH;
  const int E = in_sizes[1] / 2;
  const int nb = N;
  const int nc = (nb + CHUNK - 1) / CHUNK;  // scan chunks (<=256 supported)
  const int ngemm = ((N + 63) / 64) * 2;    // 64-row x 64-col tiles

  // ws layout (16B-aligned pieces)
  char* p = (char*)d_ws;
  float* proj = (float*)p;  p += (size_t)N * HC * 4;
  int* rc = (int*)p;        p += (((size_t)E * 4 + 15) & ~15ull);
  float* den = (float*)p;   p += (((size_t)N * HEADS * 4 + 15) & ~15ull);
  int* hist = (int*)p;      p += (((size_t)(nb + 4) * 4 + 15) & ~15ull);  // +4: headmax_u
  int* starts = (int*)p;    p += (((size_t)(nb + 1) * 4 + 15) & ~15ull);
  int* cursor = (int*)p;    p += (((size_t)(nb + 1) * 4 + 15) & ~15ull);
  int* sums = (int*)p;      p += 1024;
  unsigned* headmax_u = (unsigned*)(hist + nb);
  const size_t need_full = (size_t)(p - (char*)d_ws);
  const bool full = (ws_size >= need_full) && (nc <= 256);

  if (full) {
    hipMemsetAsync(hist, 0, (size_t)(nb + 4) * sizeof(int), stream);  // hist + headmax_u
    gemm_xW<<<ngemm, 256, 0, stream>>>(x, W, proj, N, eidx + E, hist, E);
    k_scan_a<<<nc, 256, 0, stream>>>(hist, sums, nb);
    k_scan_c<<<nc, 256, 0, stream>>>(hist, sums, starts, cursor, nb, nc);
    scatter_rc<<<(E + 255) / 256, 256, 0, stream>>>(eidx, eidx + E, cursor, rc, E);
    fused_apply<<<(N + 3) / 4, 256, 0, stream>>>(proj, rc, starts, att, out, den,
                                                 headmax_u, N);
    fix_clamp<<<(N * HEADS + 255) / 256, 256, 0, stream>>>(out, den, headmax_u, att, N);
  } else {
    // minimal-ws fallback: blockmax/corr/norm packed right after proj
    gemm_xW<<<ngemm, 256, 0, stream>>>(x, W, proj, N, nullptr, nullptr, 0);
    unsigned* bm = (unsigned*)(proj + (size_t)N * HC);
    float* cr = (float*)(bm + SCORE_BLOCKS * HEADS);
    float* norm = cr + 8;
    hipMemsetAsync(out, 0, (size_t)out_size * sizeof(float), stream);
    hipMemsetAsync(norm, 0, (size_t)N * HEADS * sizeof(float), stream);
    score_max<<<SCORE_BLOCKS, 256, 0, stream>>>(proj, eidx, eidx + E, att, bm, E);
    reduce_corr<<<1, 256, 0, stream>>>(bm, att, cr, SCORE_BLOCKS);
    edge_apply_fb<<<(E + 1) / 2, 256, 0, stream>>>(proj, eidx, eidx + E, att, cr + 4, out, norm, E);
    finalize_fb<<<(N * (HC / 4) + 255) / 256, 256, 0, stream>>>(out, norm, N);
  }
}